// Round 1
// baseline (5765.740 us; speedup 1.0000x reference)
//
#include <hip/hip_runtime.h>

#define B_    1024
#define N_    64
#define C_    512
#define NCODE 2048
#define NTOT  (B_ * N_ * C_)   // 33,554,432
#define BN_   (B_ * N_)        // 65,536

__device__ __forceinline__ float wseg(int k) {
    return k < 256 ? (1.0f / 256.0f) : (k < 384 ? (1.0f / 128.0f) : (1.0f / 64.0f));
}

// ---------------- init: rest = f, dacc = 0 ----------------
__global__ void k_init(const float* __restrict__ f, float* __restrict__ rest,
                       float* __restrict__ dacc) {
    int i = blockIdx.x * 256 + threadIdx.x;
    rest[i] = f[i];
    if (i < BN_) dacc[i] = 0.0f;
}

// ---------------- E = base @ W^T  (2048x512 = 2048x512 * 512x512^T) ----------------
__global__ __launch_bounds__(256) void k_gemm_e(const float* __restrict__ A,
                                                const float* __restrict__ Bm,
                                                float* __restrict__ E) {
    __shared__ float As[16][68];
    __shared__ float Bs[16][68];
    int tid = threadIdx.x;
    int m0 = blockIdx.x * 64, n0 = blockIdx.y * 64;
    float acc[4][4] = {};
    int tx = tid & 15, ty = tid >> 4;
    int kk = tid & 15, rr = tid >> 4;
    for (int k0 = 0; k0 < 512; k0 += 16) {
        #pragma unroll
        for (int i = 0; i < 4; ++i) {
            As[kk][rr + i * 16] = A[(m0 + rr + i * 16) * 512 + k0 + kk];
            Bs[kk][rr + i * 16] = Bm[(n0 + rr + i * 16) * 512 + k0 + kk];
        }
        __syncthreads();
        #pragma unroll
        for (int k = 0; k < 16; ++k) {
            float4 a = *(const float4*)&As[k][ty * 4];
            float4 b = *(const float4*)&Bs[k][tx * 4];
            acc[0][0] = fmaf(a.x, b.x, acc[0][0]);
            acc[0][1] = fmaf(a.x, b.y, acc[0][1]);
            acc[0][2] = fmaf(a.x, b.z, acc[0][2]);
            acc[0][3] = fmaf(a.x, b.w, acc[0][3]);
            acc[1][0] = fmaf(a.y, b.x, acc[1][0]);
            acc[1][1] = fmaf(a.y, b.y, acc[1][1]);
            acc[1][2] = fmaf(a.y, b.z, acc[1][2]);
            acc[1][3] = fmaf(a.y, b.w, acc[1][3]);
            acc[2][0] = fmaf(a.z, b.x, acc[2][0]);
            acc[2][1] = fmaf(a.z, b.y, acc[2][1]);
            acc[2][2] = fmaf(a.z, b.z, acc[2][2]);
            acc[2][3] = fmaf(a.z, b.w, acc[2][3]);
            acc[3][0] = fmaf(a.w, b.x, acc[3][0]);
            acc[3][1] = fmaf(a.w, b.y, acc[3][1]);
            acc[3][2] = fmaf(a.w, b.z, acc[3][2]);
            acc[3][3] = fmaf(a.w, b.w, acc[3][3]);
        }
        __syncthreads();
    }
    #pragma unroll
    for (int i = 0; i < 4; ++i)
        #pragma unroll
        for (int j = 0; j < 4; ++j)
            E[(m0 + ty * 4 + i) * 512 + n0 + tx * 4 + j] = acc[i][j];
}

// ---------------- weT[k][c] = E[c][k] * wseg(k) ----------------
__global__ void k_wet(const float* __restrict__ E, float* __restrict__ weT) {
    int tid = blockIdx.x * 256 + threadIdx.x;   // 512*2048
    int k = tid >> 11, c = tid & 2047;
    weT[tid] = E[c * 512 + k] * wseg(k);
}

// ---------------- enorm[c] = sum_k wseg(k)*E[c][k]^2 ----------------
__global__ void k_enorm(const float* __restrict__ E, float* __restrict__ enorm) {
    int c = blockIdx.x * 256 + threadIdx.x;   // 2048
    float s = 0.0f;
    for (int k = 0; k < 512; ++k) {
        float v = E[c * 512 + k];
        s = fmaf(wseg(k) * v, v, s);
    }
    enorm[c] = s;
}

// ---------------- downsample: q[m][c] = mean over chunk of rest ----------------
__global__ void k_down(const float* __restrict__ rest, float* __restrict__ q, int shift) {
    int tid = blockIdx.x * 256 + threadIdx.x;    // M*512
    int m = tid >> 9, c = tid & 511;
    int pn = 1 << shift;
    int r = 64 >> shift;
    int b = m >> shift, p = m & (pn - 1);
    const float* src = rest + ((b << 6) + p * r) * 512 + c;
    float s = 0.0f;
    for (int j = 0; j < r; ++j) s += src[j * 512];
    q[tid] = s * (1.0f / (float)r);
}

// ---------------- score GEMM + fused per-tile argmin ----------------
// scores[m][c] = enorm[c] - 2 * dot(q[m], we[c]);  partial[m][ntile] = (minval, minidx)
__global__ __launch_bounds__(256) void k_score(const float* __restrict__ q,
                                               const float* __restrict__ weT,
                                               const float* __restrict__ enorm,
                                               float2* __restrict__ partial) {
    __shared__ float As[16][68];
    __shared__ float Bs[16][68];
    __shared__ float rval[64][17];
    __shared__ int   ridx[64][17];
    int tid = threadIdx.x;
    int m0 = blockIdx.x * 64, n0 = blockIdx.y * 64;
    float acc[4][4] = {};
    int tx = tid & 15, ty = tid >> 4;
    int kkA = tid & 15, mrA = tid >> 4;     // A staging: 64B-coalesced groups
    int nnB = tid & 63, krB = tid >> 6;     // B staging: fully coalesced
    for (int k0 = 0; k0 < 512; k0 += 16) {
        #pragma unroll
        for (int i = 0; i < 4; ++i)
            As[kkA][mrA + i * 16] = q[(m0 + mrA + i * 16) * 512 + k0 + kkA];
        #pragma unroll
        for (int i = 0; i < 4; ++i)
            Bs[krB + i * 4][nnB] = weT[(k0 + krB + i * 4) * 2048 + n0 + nnB];
        __syncthreads();
        #pragma unroll
        for (int k = 0; k < 16; ++k) {
            float4 a = *(const float4*)&As[k][ty * 4];
            float4 b = *(const float4*)&Bs[k][tx * 4];
            acc[0][0] = fmaf(a.x, b.x, acc[0][0]);
            acc[0][1] = fmaf(a.x, b.y, acc[0][1]);
            acc[0][2] = fmaf(a.x, b.z, acc[0][2]);
            acc[0][3] = fmaf(a.x, b.w, acc[0][3]);
            acc[1][0] = fmaf(a.y, b.x, acc[1][0]);
            acc[1][1] = fmaf(a.y, b.y, acc[1][1]);
            acc[1][2] = fmaf(a.y, b.z, acc[1][2]);
            acc[1][3] = fmaf(a.y, b.w, acc[1][3]);
            acc[2][0] = fmaf(a.z, b.x, acc[2][0]);
            acc[2][1] = fmaf(a.z, b.y, acc[2][1]);
            acc[2][2] = fmaf(a.z, b.z, acc[2][2]);
            acc[2][3] = fmaf(a.z, b.w, acc[2][3]);
            acc[3][0] = fmaf(a.w, b.x, acc[3][0]);
            acc[3][1] = fmaf(a.w, b.y, acc[3][1]);
            acc[3][2] = fmaf(a.w, b.z, acc[3][2]);
            acc[3][3] = fmaf(a.w, b.w, acc[3][3]);
        }
        __syncthreads();
    }
    // per-thread min over its 4 cols, strict < keeps lowest code index
    #pragma unroll
    for (int i = 0; i < 4; ++i) {
        float bv = INFINITY; int bi = 0;
        #pragma unroll
        for (int j = 0; j < 4; ++j) {
            int code = n0 + tx * 4 + j;
            float s = enorm[code] - 2.0f * acc[i][j];
            if (s < bv) { bv = s; bi = code; }
        }
        rval[ty * 4 + i][tx] = bv;
        ridx[ty * 4 + i][tx] = bi;
    }
    __syncthreads();
    if (tid < 64) {
        float bv = rval[tid][0]; int bi = ridx[tid][0];
        #pragma unroll
        for (int t = 1; t < 16; ++t) {
            float v = rval[tid][t];
            if (v < bv) { bv = v; bi = ridx[tid][t]; }
        }
        partial[(m0 + tid) * 32 + blockIdx.y] = make_float2(bv, __int_as_float(bi));
    }
}

// ---------------- argmin reduce over 32 tiles ----------------
__global__ void k_reduce(const float2* __restrict__ partial, int* __restrict__ idx, int M) {
    int m = blockIdx.x * 256 + threadIdx.x;
    if (m >= M) return;
    float bv = INFINITY; int bi = 0;
    for (int t = 0; t < 32; ++t) {
        float2 p = partial[m * 32 + t];
        if (p.x < bv) { bv = p.x; bi = __float_as_int(p.y); }
    }
    idx[m] = bi;
}

// ---------------- update: rest -= upsample(E[idx]); dacc += sum_c wseg*rest^2 ----------------
__global__ __launch_bounds__(256) void k_update(const float* __restrict__ E,
                                                const int* __restrict__ idx,
                                                float* __restrict__ rest,
                                                float* __restrict__ dacc, int pn) {
    int row = blockIdx.x;               // b*64 + n
    int b = row >> 6, n = row & 63;
    float src = (n + 0.5f) * ((float)pn / 64.0f) - 0.5f;
    src = fminf(fmaxf(src, 0.0f), (float)(pn - 1));
    int i0 = (int)floorf(src);
    int i1 = min(i0 + 1, pn - 1);
    float w = src - (float)i0;
    int c0 = idx[b * pn + i0];
    int c1 = idx[b * pn + i1];
    const float* e0 = E + c0 * 512;
    const float* e1 = E + c1 * 512;
    float* r = rest + row * 512;
    int t = threadIdx.x;
    float s = 0.0f;
    #pragma unroll
    for (int u = 0; u < 2; ++u) {
        int c = t + u * 256;
        float h = (1.0f - w) * e0[c] + w * e1[c];
        float v = r[c] - h;
        r[c] = v;
        s = fmaf(wseg(c) * v, v, s);
    }
    __shared__ float red[256];
    red[t] = s;
    __syncthreads();
    for (int off = 128; off > 0; off >>= 1) {
        if (t < off) red[t] += red[t + off];
        __syncthreads();
    }
    if (t == 0) dacc[row] += red[0];
}

// ---------------- finalize ----------------
__global__ void k_out0(const float* __restrict__ f, float* __restrict__ out) {
    int i = blockIdx.x * 256 + threadIdx.x;
    out[i] = f[i] - out[i];                 // out currently holds rest
}
__global__ void k_out12(const float* __restrict__ dacc, float* __restrict__ out) {
    int i = blockIdx.x * 256 + threadIdx.x; // 65536
    float d = dacc[i];
    out[i] = d * (0.25f / 7.0f);
    out[BN_ + i] = d * (1.0f / 7.0f);
}

extern "C" void kernel_launch(void* const* d_in, const int* in_sizes, int n_in,
                              void* d_out, int out_size, void* d_ws, size_t ws_size,
                              hipStream_t stream) {
    const float* f    = (const float*)d_in[0];   // 1024*64*512
    const float* base = (const float*)d_in[1];   // 2048*512
    const float* W    = (const float*)d_in[2];   // 512*512
    float* out = (float*)d_out;

    // d_out[0 .. NTOT) doubles as the f_rest buffer during the pipeline.
    float* rest = out;

    char* ws = (char*)d_ws;
    float*  E       = (float*)ws;               ws += (size_t)NCODE * 512 * 4;   // 4 MB
    float*  weT     = (float*)ws;               ws += (size_t)512 * NCODE * 4;   // 4 MB
    float*  q       = (float*)ws;               ws += (size_t)32768 * 512 * 4;   // 64 MB
    float2* partial = (float2*)ws;              ws += (size_t)65536 * 32 * 8;    // 16 MB
    float*  dacc    = (float*)ws;               ws += (size_t)BN_ * 4;           // 256 KB
    int*    idxb    = (int*)ws;                 ws += (size_t)BN_ * 4;           // 256 KB
    float*  enorm   = (float*)ws;               ws += (size_t)NCODE * 4;         // 8 KB

    k_init<<<NTOT / 256, 256, 0, stream>>>(f, rest, dacc);
    k_gemm_e<<<dim3(NCODE / 64, 512 / 64), 256, 0, stream>>>(base, W, E);
    k_wet<<<(512 * NCODE) / 256, 256, 0, stream>>>(E, weT);
    k_enorm<<<NCODE / 256, 256, 0, stream>>>(E, enorm);

    const int scales[7] = {1, 2, 4, 8, 16, 32, 64};
    for (int si = 0; si < 7; ++si) {
        int pn = scales[si];
        int M = 1024 * pn;
        const float* qp;
        if (pn < 64) {
            int shift = 0; while ((1 << shift) != pn) ++shift;
            k_down<<<(M * 512) / 256, 256, 0, stream>>>(rest, q, shift);
            qp = q;
        } else {
            qp = rest;   // identity downsample at pn=64, layout matches exactly
        }
        k_score<<<dim3(M / 64, NCODE / 64), 256, 0, stream>>>(qp, weT, enorm, partial);
        k_reduce<<<(M + 255) / 256, 256, 0, stream>>>(partial, idxb, M);
        k_update<<<BN_, 256, 0, stream>>>(E, idxb, rest, dacc, pn);
    }

    k_out0<<<NTOT / 256, 256, 0, stream>>>(f, out);
    k_out12<<<BN_ / 256, 256, 0, stream>>>(dacc, out + NTOT);
}

// Round 2
// 1921.626 us; speedup vs baseline: 3.0004x; 3.0004x over previous
//
#include <hip/hip_runtime.h>

typedef __attribute__((ext_vector_type(8))) short short8;
typedef __attribute__((ext_vector_type(4))) float f32x4;

#define B_    1024
#define N_    64
#define C_    512
#define NCODE 2048
#define NTOT  (B_ * N_ * C_)   // 33,554,432
#define BN_   (B_ * N_)        // 65,536
#define DELTA 2e-3f

__device__ __forceinline__ float wseg(int k) {
    return k < 256 ? (1.0f / 256.0f) : (k < 384 ? (1.0f / 128.0f) : (1.0f / 64.0f));
}
// RNE float->bf16 bits (finite inputs only)
__device__ __forceinline__ unsigned short f2bf(float x) {
    unsigned u = __float_as_uint(x);
    unsigned r = (u + 0x7fffu + ((u >> 16) & 1u)) >> 16;
    return (unsigned short)r;
}
__device__ __forceinline__ float bf2f(unsigned short b) {
    return __uint_as_float(((unsigned)b) << 16);
}

// ---------------- init: rest = f, dacc = 0 ----------------
__global__ void k_init(const float* __restrict__ f, float* __restrict__ rest,
                       float* __restrict__ dacc) {
    int i = blockIdx.x * 256 + threadIdx.x;
    rest[i] = f[i];
    if (i < BN_) dacc[i] = 0.0f;
}

// ---------------- E = base @ W^T ----------------
__global__ __launch_bounds__(256) void k_gemm_e(const float* __restrict__ A,
                                                const float* __restrict__ Bm,
                                                float* __restrict__ E) {
    __shared__ float As[16][68];
    __shared__ float Bs[16][68];
    int tid = threadIdx.x;
    int m0 = blockIdx.x * 64, n0 = blockIdx.y * 64;
    float acc[4][4] = {};
    int tx = tid & 15, ty = tid >> 4;
    int kk = tid & 15, rr = tid >> 4;
    for (int k0 = 0; k0 < 512; k0 += 16) {
        #pragma unroll
        for (int i = 0; i < 4; ++i) {
            As[kk][rr + i * 16] = A[(m0 + rr + i * 16) * 512 + k0 + kk];
            Bs[kk][rr + i * 16] = Bm[(n0 + rr + i * 16) * 512 + k0 + kk];
        }
        __syncthreads();
        #pragma unroll
        for (int k = 0; k < 16; ++k) {
            float4 a = *(const float4*)&As[k][ty * 4];
            float4 b = *(const float4*)&Bs[k][tx * 4];
            #pragma unroll
            for (int i = 0; i < 4; ++i) {
                float av = ((const float*)&a)[i];
                acc[i][0] = fmaf(av, b.x, acc[i][0]);
                acc[i][1] = fmaf(av, b.y, acc[i][1]);
                acc[i][2] = fmaf(av, b.z, acc[i][2]);
                acc[i][3] = fmaf(av, b.w, acc[i][3]);
            }
        }
        __syncthreads();
    }
    #pragma unroll
    for (int i = 0; i < 4; ++i)
        #pragma unroll
        for (int j = 0; j < 4; ++j)
            E[(m0 + ty * 4 + i) * 512 + n0 + tx * 4 + j] = acc[i][j];
}

// ---------------- split weighted codes to bf16 hi/lo, code-major [c][k] ----------------
__global__ void k_wek(const float* __restrict__ E, short* __restrict__ wh,
                      short* __restrict__ wl) {
    int tid = blockIdx.x * 256 + threadIdx.x;   // 2048*512
    int k = tid & 511;
    float we = E[tid] * wseg(k);                 // exact (w = 2^-s)
    unsigned short hb = f2bf(we);
    unsigned short lb = f2bf(we - bf2f(hb));
    wh[tid] = (short)hb;
    wl[tid] = (short)lb;
}

// ---------------- enorm[c] = sum_k wseg(k)*E[c][k]^2 ----------------
__global__ void k_enorm(const float* __restrict__ E, float* __restrict__ enorm) {
    int c = blockIdx.x * 256 + threadIdx.x;   // 2048
    float s = 0.0f;
    for (int k = 0; k < 512; ++k) {
        float v = E[c * 512 + k];
        s = fmaf(wseg(k) * v, v, s);
    }
    enorm[c] = s;
}

// ---------------- downsample: q[m][c] = mean over chunk of rest ----------------
__global__ void k_down(const float* __restrict__ rest, float* __restrict__ q, int shift) {
    int tid = blockIdx.x * 256 + threadIdx.x;    // M*512
    int m = tid >> 9, c = tid & 511;
    int pn = 1 << shift;
    int r = 64 >> shift;
    int b = m >> shift, p = m & (pn - 1);
    const float* src = rest + ((b << 6) + p * r) * 512 + c;
    float s = 0.0f;
    for (int j = 0; j < r; ++j) s += src[j * 512];
    q[tid] = s * (1.0f / (float)r);
}

// ---------------- MFMA score GEMM (bf16 hi/lo x3) + per-tile best2 ----------------
// scores[m][n] = enorm[n] - 2 * sum_k q[m][k]*we[n][k]
__global__ __launch_bounds__(256) void k_score_mfma(
        const float* __restrict__ qf, const short* __restrict__ wh,
        const short* __restrict__ wl, const float* __restrict__ enorm,
        float4* __restrict__ partial, int M) {
    __shared__ __align__(16) char smem[66560];
    short* Ah = (short*)smem;             // [128][32] bf16 hi
    short* Al = (short*)(smem + 8192);    // lo
    short* Bh = (short*)(smem + 16384);   // [128 codes][32]
    short* Bl = (short*)(smem + 24576);
    float* sc  = (float*)smem;            // [128][129] overlay (epilogue only)
    float* ensh = (float*)(smem + 66048); // [128]

    int tid = threadIdx.x;
    int bx = blockIdx.x;                  // col tile (16)
    int m0 = blockIdx.y * 128;
    int n0 = bx * 128;
    if (tid < 128) ensh[tid] = enorm[n0 + tid];

    int lane = tid & 63, wave = tid >> 6;
    int wrow = (wave & 1) * 64, wcol = (wave >> 1) * 64;

    f32x4 acc[4][4];
    #pragma unroll
    for (int i = 0; i < 4; ++i)
        #pragma unroll
        for (int j = 0; j < 4; ++j)
            acc[i][j] = (f32x4){0.f, 0.f, 0.f, 0.f};

    int arow = tid >> 1, akh = (tid & 1) * 16;
    const float* agp = qf + (size_t)(m0 + arow) * 512 + akh;

    float4 ra[2][4];
    short8 rbh[2][2], rbl[2][2];

    // prologue loads (k0 = 0)
    #pragma unroll
    for (int i = 0; i < 4; ++i) ra[0][i] = *(const float4*)(agp + i * 4);
    #pragma unroll
    for (int i = 0; i < 2; ++i) {
        int c = i * 256 + tid;
        size_t g = (size_t)(n0 + (c >> 2)) * 512 + (c & 3) * 8;
        rbh[0][i] = *(const short8*)(wh + g);
        rbl[0][i] = *(const short8*)(wl + g);
    }

    #pragma unroll
    for (int k0i = 0; k0i < 16; ++k0i) {
        int p = k0i & 1;
        __syncthreads();                       // prev compute done; LDS free
        // A: convert fp32 -> hi/lo, write
        #pragma unroll
        for (int h = 0; h < 2; ++h) {
            short8 vh, vl;
            #pragma unroll
            for (int j = 0; j < 8; ++j) {
                float x = ra[p][h * 2 + (j >> 2)][j & 3];
                unsigned short hb = f2bf(x);
                vh[j] = (short)hb;
                vl[j] = (short)f2bf(x - bf2f(hb));
            }
            *(short8*)&Ah[arow * 32 + akh + h * 8] = vh;
            *(short8*)&Al[arow * 32 + akh + h * 8] = vl;
        }
        #pragma unroll
        for (int i = 0; i < 2; ++i) {
            int c = i * 256 + tid;
            *(short8*)&Bh[c * 8] = rbh[p][i];
            *(short8*)&Bl[c * 8] = rbl[p][i];
        }
        __syncthreads();
        // prefetch next K-step (hides HBM latency under MFMAs)
        if (k0i < 15) {
            int k0 = (k0i + 1) * 32;
            #pragma unroll
            for (int i = 0; i < 4; ++i) ra[p ^ 1][i] = *(const float4*)(agp + k0 + i * 4);
            #pragma unroll
            for (int i = 0; i < 2; ++i) {
                int c = i * 256 + tid;
                size_t g = (size_t)(n0 + (c >> 2)) * 512 + k0 + (c & 3) * 8;
                rbh[p ^ 1][i] = *(const short8*)(wh + g);
                rbl[p ^ 1][i] = *(const short8*)(wl + g);
            }
        }
        // fragments + MFMA
        int ko = (lane >> 4) * 8;
        short8 bh[4], bl[4];
        #pragma unroll
        for (int fj = 0; fj < 4; ++fj) {
            int n = wcol + fj * 16 + (lane & 15);
            bh[fj] = *(const short8*)&Bh[n * 32 + ko];
            bl[fj] = *(const short8*)&Bl[n * 32 + ko];
        }
        #pragma unroll
        for (int fi = 0; fi < 4; ++fi) {
            int mr = wrow + fi * 16 + (lane & 15);
            short8 ah = *(const short8*)&Ah[mr * 32 + ko];
            short8 al = *(const short8*)&Al[mr * 32 + ko];
            #pragma unroll
            for (int fj = 0; fj < 4; ++fj) {
                acc[fi][fj] = __builtin_amdgcn_mfma_f32_16x16x32_bf16(ah, bh[fj], acc[fi][fj], 0, 0, 0);
                acc[fi][fj] = __builtin_amdgcn_mfma_f32_16x16x32_bf16(ah, bl[fj], acc[fi][fj], 0, 0, 0);
                acc[fi][fj] = __builtin_amdgcn_mfma_f32_16x16x32_bf16(al, bh[fj], acc[fi][fj], 0, 0, 0);
            }
        }
    }
    __syncthreads();   // all frag reads done before sc overlays A/B
    // scores -> LDS
    #pragma unroll
    for (int fi = 0; fi < 4; ++fi)
        #pragma unroll
        for (int fj = 0; fj < 4; ++fj)
            #pragma unroll
            for (int r = 0; r < 4; ++r) {
                int ml = wrow + fi * 16 + (lane >> 4) * 4 + r;
                int nl = wcol + fj * 16 + (lane & 15);
                sc[ml * 129 + nl] = ensh[nl] - 2.0f * acc[fi][fj][r];
            }
    __syncthreads();
    // per-row best2 over the 128 cols of this tile (strict <, ascending idx)
    if (tid < 128) {
        float v1 = INFINITY, v2 = INFINITY;
        int i1 = NCODE, i2 = NCODE;
        for (int j = 0; j < 128; ++j) {
            float v = sc[tid * 129 + j];
            int ii = n0 + j;
            if (v < v1) { v2 = v1; i2 = i1; v1 = v; i1 = ii; }
            else if (v < v2) { v2 = v; i2 = ii; }
        }
        partial[(size_t)(m0 + tid) * 16 + bx] =
            make_float4(v1, __int_as_float(i1), v2, __int_as_float(i2));
    }
}

// ---------------- rescue: exact fp32 rescore of near-min candidates ----------------
__global__ __launch_bounds__(256) void k_rescue(
        const float4* __restrict__ partial, const float* __restrict__ qf,
        const float* __restrict__ E, const float* __restrict__ enorm,
        int* __restrict__ idxb) {
    int wid = (blockIdx.x * 256 + threadIdx.x) >> 6;   // one wave per query
    int lane = threadIdx.x & 63;
    float4 p;
    if (lane < 16) p = partial[(size_t)wid * 16 + lane];
    else p = make_float4(INFINITY, __int_as_float(NCODE), INFINITY, __int_as_float(NCODE));
    float bv = p.x;
    #pragma unroll
    for (int d = 1; d < 64; d <<= 1) bv = fminf(bv, __shfl_xor(bv, d));
    float thresh = bv + DELTA;
    unsigned long long m1 = __ballot(lane < 16 && p.x <= thresh);
    unsigned long long m2 = __ballot(lane < 16 && p.z <= thresh);
    const float* q = qf + (size_t)wid * 512 + lane * 8;
    float4 q0 = *(const float4*)q;
    float4 q1 = *(const float4*)(q + 4);
    float w = wseg(lane * 8);                 // segment bounds are multiples of 8
    float qw0 = q0.x * w, qw1 = q0.y * w, qw2 = q0.z * w, qw3 = q0.w * w;
    float qw4 = q1.x * w, qw5 = q1.y * w, qw6 = q1.z * w, qw7 = q1.w * w;
    float bs = INFINITY; int bi = NCODE;
    while (m1 | m2) {
        int ci;
        if (m1) {
            int src = __ffsll((long long)m1) - 1; m1 &= m1 - 1;
            ci = __shfl(__float_as_int(p.y), src);
        } else {
            int src = __ffsll((long long)m2) - 1; m2 &= m2 - 1;
            ci = __shfl(__float_as_int(p.w), src);
        }
        const float* e = E + (size_t)ci * 512 + lane * 8;
        float4 e0 = *(const float4*)e;
        float4 e1 = *(const float4*)(e + 4);
        float a = 0.f;
        a = fmaf(qw0, e0.x, a); a = fmaf(qw1, e0.y, a);
        a = fmaf(qw2, e0.z, a); a = fmaf(qw3, e0.w, a);
        a = fmaf(qw4, e1.x, a); a = fmaf(qw5, e1.y, a);
        a = fmaf(qw6, e1.z, a); a = fmaf(qw7, e1.w, a);
        #pragma unroll
        for (int d = 1; d < 64; d <<= 1) a += __shfl_xor(a, d);
        float s = enorm[ci] - 2.0f * a;
        if (s < bs || (s == bs && ci < bi)) { bs = s; bi = ci; }
    }
    if (lane == 0) idxb[wid] = bi;
}

// ---------------- update: rest -= upsample(E[idx]); dacc += sum_c wseg*rest^2 ----------------
__global__ __launch_bounds__(256) void k_update(const float* __restrict__ E,
                                                const int* __restrict__ idx,
                                                float* __restrict__ rest,
                                                float* __restrict__ dacc, int pn) {
    int row = blockIdx.x;               // b*64 + n
    int b = row >> 6, n = row & 63;
    float src = (n + 0.5f) * ((float)pn / 64.0f) - 0.5f;
    src = fminf(fmaxf(src, 0.0f), (float)(pn - 1));
    int i0 = (int)floorf(src);
    int i1 = min(i0 + 1, pn - 1);
    float w = src - (float)i0;
    int c0 = idx[b * pn + i0];
    int c1 = idx[b * pn + i1];
    const float* e0 = E + c0 * 512;
    const float* e1 = E + c1 * 512;
    float* r = rest + row * 512;
    int t = threadIdx.x;
    float s = 0.0f;
    #pragma unroll
    for (int u = 0; u < 2; ++u) {
        int c = t + u * 256;
        float h = (1.0f - w) * e0[c] + w * e1[c];
        float v = r[c] - h;
        r[c] = v;
        s = fmaf(wseg(c) * v, v, s);
    }
    __shared__ float red[256];
    red[t] = s;
    __syncthreads();
    for (int off = 128; off > 0; off >>= 1) {
        if (t < off) red[t] += red[t + off];
        __syncthreads();
    }
    if (t == 0) dacc[row] += red[0];
}

// ---------------- finalize ----------------
__global__ void k_out0(const float* __restrict__ f, float* __restrict__ out) {
    int i = blockIdx.x * 256 + threadIdx.x;
    out[i] = f[i] - out[i];                 // out currently holds rest
}
__global__ void k_out12(const float* __restrict__ dacc, float* __restrict__ out) {
    int i = blockIdx.x * 256 + threadIdx.x; // 65536
    float d = dacc[i];
    out[i] = d * (0.25f / 7.0f);
    out[BN_ + i] = d * (1.0f / 7.0f);
}

extern "C" void kernel_launch(void* const* d_in, const int* in_sizes, int n_in,
                              void* d_out, int out_size, void* d_ws, size_t ws_size,
                              hipStream_t stream) {
    const float* f    = (const float*)d_in[0];
    const float* base = (const float*)d_in[1];
    const float* W    = (const float*)d_in[2];
    float* out = (float*)d_out;
    float* rest = out;                       // d_out doubles as f_rest

    char* ws = (char*)d_ws;
    float*  E       = (float*)ws;  ws += (size_t)NCODE * 512 * 4;     // 4 MB
    short*  wekh    = (short*)ws;  ws += (size_t)NCODE * 512 * 2;     // 2 MB
    short*  wekl    = (short*)ws;  ws += (size_t)NCODE * 512 * 2;     // 2 MB
    float*  qbuf    = (float*)ws;  ws += (size_t)32768 * 512 * 4;     // 64 MB
    float4* partial = (float4*)ws; ws += (size_t)65536 * 16 * 16;     // 16 MB
    float*  dacc    = (float*)ws;  ws += (size_t)BN_ * 4;
    int*    idxb    = (int*)ws;    ws += (size_t)BN_ * 4;
    float*  enorm   = (float*)ws;  ws += (size_t)NCODE * 4;

    k_init<<<NTOT / 256, 256, 0, stream>>>(f, rest, dacc);
    k_gemm_e<<<dim3(NCODE / 64, 512 / 64), 256, 0, stream>>>(base, W, E);
    k_wek<<<(NCODE * 512) / 256, 256, 0, stream>>>(E, wekh, wekl);
    k_enorm<<<NCODE / 256, 256, 0, stream>>>(E, enorm);

    const int scales[7] = {1, 2, 4, 8, 16, 32, 64};
    for (int si = 0; si < 7; ++si) {
        int pn = scales[si];
        int M = 1024 * pn;
        const float* qp;
        if (pn < 64) {
            int shift = 0; while ((1 << shift) != pn) ++shift;
            k_down<<<(M * 512) / 256, 256, 0, stream>>>(rest, qbuf, shift);
            qp = qbuf;
        } else {
            qp = rest;                       // identity downsample at pn=64
        }
        k_score_mfma<<<dim3(16, M / 128), 256, 0, stream>>>(qp, wekh, wekl, enorm, partial, M);
        k_rescue<<<M / 4, 256, 0, stream>>>(partial, qp, E, enorm, idxb);
        k_update<<<BN_, 256, 0, stream>>>(E, idxb, rest, dacc, pn);
    }

    k_out0<<<NTOT / 256, 256, 0, stream>>>(f, out);
    k_out12<<<BN_ / 256, 256, 0, stream>>>(dacc, out + NTOT);
}

// Round 3
// 1210.416 us; speedup vs baseline: 4.7634x; 1.5876x over previous
//
#include <hip/hip_runtime.h>

typedef __attribute__((ext_vector_type(8))) _Float16 f16x8;
typedef __attribute__((ext_vector_type(4))) float f32x4;

#define B_    1024
#define C_    512
#define NCODE 2048
#define NTOT  (B_ * 64 * C_)   // 33,554,432
#define BN_   (B_ * 64)        // 65,536
#define DELTA 3e-3f

__device__ __forceinline__ float wseg(int k) {
    return k < 256 ? (1.0f / 256.0f) : (k < 384 ? (1.0f / 128.0f) : (1.0f / 64.0f));
}

// ---------------- E = base @ W^T ----------------
__global__ __launch_bounds__(256) void k_gemm_e(const float* __restrict__ A,
                                                const float* __restrict__ Bm,
                                                float* __restrict__ E) {
    __shared__ float As[16][68];
    __shared__ float Bs[16][68];
    int tid = threadIdx.x;
    int m0 = blockIdx.x * 64, n0 = blockIdx.y * 64;
    float acc[4][4] = {};
    int tx = tid & 15, ty = tid >> 4;
    int kk = tid & 15, rr = tid >> 4;
    for (int k0 = 0; k0 < 512; k0 += 16) {
        #pragma unroll
        for (int i = 0; i < 4; ++i) {
            As[kk][rr + i * 16] = A[(m0 + rr + i * 16) * 512 + k0 + kk];
            Bs[kk][rr + i * 16] = Bm[(n0 + rr + i * 16) * 512 + k0 + kk];
        }
        __syncthreads();
        #pragma unroll
        for (int k = 0; k < 16; ++k) {
            float4 a = *(const float4*)&As[k][ty * 4];
            float4 b = *(const float4*)&Bs[k][tx * 4];
            #pragma unroll
            for (int i = 0; i < 4; ++i) {
                float av = ((const float*)&a)[i];
                acc[i][0] = fmaf(av, b.x, acc[i][0]);
                acc[i][1] = fmaf(av, b.y, acc[i][1]);
                acc[i][2] = fmaf(av, b.z, acc[i][2]);
                acc[i][3] = fmaf(av, b.w, acc[i][3]);
            }
        }
        __syncthreads();
    }
    #pragma unroll
    for (int i = 0; i < 4; ++i)
        #pragma unroll
        for (int j = 0; j < 4; ++j)
            E[(m0 + ty * 4 + i) * 512 + n0 + tx * 4 + j] = acc[i][j];
}

// ---------------- weighted codes -> f16, code-major [c][k] ----------------
__global__ void k_wek16(const float* __restrict__ E, _Float16* __restrict__ wk) {
    int tid = blockIdx.x * 256 + threadIdx.x;   // 2048*512
    int k = tid & 511;
    wk[tid] = (_Float16)(E[tid] * wseg(k));     // w = 2^-s, exact scale
}

// ---------------- enorm[c] = sum_k wseg(k)*E[c][k]^2 ----------------
__global__ void k_enorm(const float* __restrict__ E, float* __restrict__ enorm) {
    int c = blockIdx.x * 256 + threadIdx.x;   // 2048
    float s = 0.0f;
    for (int k = 0; k < 512; ++k) {
        float v = E[c * 512 + k];
        s = fmaf(wseg(k) * v, v, s);
    }
    enorm[c] = s;
}

// ---------------- initial downsample (pn=1): q = mean_n f ----------------
__global__ __launch_bounds__(256) void k_down0(const float* __restrict__ f,
                                               _Float16* __restrict__ q16,
                                               float* __restrict__ qf) {
    int b = blockIdx.x, t = threadIdx.x;
    const float* src = f + (size_t)b * 64 * 512;
    float s0 = 0.f, s1 = 0.f;
    for (int n = 0; n < 64; ++n) {
        s0 += src[n * 512 + t];
        s1 += src[n * 512 + t + 256];
    }
    s0 *= (1.0f / 64.0f); s1 *= (1.0f / 64.0f);
    q16[(size_t)b * 512 + t] = (_Float16)s0;
    q16[(size_t)b * 512 + t + 256] = (_Float16)s1;
    qf[(size_t)b * 512 + t] = s0;
    qf[(size_t)b * 512 + t + 256] = s1;
}

// ---------------- MFMA score GEMM (fp16) + per-tile best2 ----------------
// score[m][n] = enorm[n] - 2 * sum_k q[m][k]*we[n][k]
__global__ __launch_bounds__(256, 4) void k_score_f16(
        const _Float16* __restrict__ q16, const _Float16* __restrict__ wek,
        const float* __restrict__ enorm, float4* __restrict__ partial) {
    // [A0 8K][A1 8K][B0 8K][B1 8K][ensh 512B][bb 4K] = 37376 B
    __shared__ __align__(16) char smem[37376];
    float*  ensh = (float*)(smem + 32768);
    float4* bb   = (float4*)(smem + 33280);

    int tid = threadIdx.x;
    int bx = blockIdx.x;                 // 16 col tiles
    int m0 = blockIdx.y * 128, n0 = bx * 128;
    if (tid < 128) ensh[tid] = enorm[n0 + tid];

    int lane = tid & 63, wave = tid >> 6;
    int wrow = (wave & 1) * 64, wcol = (wave >> 1) * 64;
    int lx = lane & 15, cg = lane >> 4;

    // staging sources: linear LDS chunk L -> (row=L>>2, c=L&3); global chunk = c ^ (row&3)
    int r0 = tid >> 2, c0 = tid & 3;
    int cs0 = (c0 ^ (r0 & 3)) * 8;
    const _Float16* gqa0 = q16 + (size_t)(m0 + r0) * 512 + cs0;
    const _Float16* gqa1 = q16 + (size_t)(m0 + 64 + r0) * 512 + cs0;
    const _Float16* gwb0 = wek + (size_t)(n0 + r0) * 512 + cs0;
    const _Float16* gwb1 = wek + (size_t)(n0 + 64 + r0) * 512 + cs0;

    #define GLL(gp, loff) __builtin_amdgcn_global_load_lds( \
        (const __attribute__((address_space(1))) unsigned int*)(gp), \
        (__attribute__((address_space(3))) unsigned int*)(smem + (loff)), 16, 0, 0)

    auto stage = [&](int p, int k0) {
        GLL(gqa0 + k0, p * 8192 + tid * 16);
        GLL(gqa1 + k0, p * 8192 + 4096 + tid * 16);
        GLL(gwb0 + k0, 16384 + p * 8192 + tid * 16);
        GLL(gwb1 + k0, 16384 + p * 8192 + 4096 + tid * 16);
    };

    f32x4 acc[4][4];
    #pragma unroll
    for (int i = 0; i < 4; ++i)
        #pragma unroll
        for (int j = 0; j < 4; ++j)
            acc[i][j] = (f32x4){0.f, 0.f, 0.f, 0.f};

    // fragment read bases (bytes): row-major [128][32] f16, chunk-XOR swizzled
    int abase = (wrow + lx) * 64 + ((cg ^ (lx & 3)) * 16);
    int bbase = (wcol + lx) * 64 + ((cg ^ (lx & 3)) * 16);

    stage(0, 0);
    __syncthreads();

    #pragma unroll
    for (int ks = 0; ks < 16; ++ks) {
        int p = ks & 1;
        if (ks < 15) stage(p ^ 1, (ks + 1) * 32);
        f16x8 af[4], bf[4];
        #pragma unroll
        for (int i = 0; i < 4; ++i) {
            af[i] = *(const f16x8*)(smem + p * 8192 + abase + i * 1024);
            bf[i] = *(const f16x8*)(smem + 16384 + p * 8192 + bbase + i * 1024);
        }
        #pragma unroll
        for (int i = 0; i < 4; ++i)
            #pragma unroll
            for (int j = 0; j < 4; ++j)
                acc[i][j] = __builtin_amdgcn_mfma_f32_16x16x32_f16(af[i], bf[j], acc[i][j], 0, 0, 0);
        __syncthreads();
    }

    // in-register best2: rows live in 16-lane groups (C layout: row=..+ (lane>>4)*4+r, col=..+(lane&15))
    #pragma unroll
    for (int fi = 0; fi < 4; ++fi) {
        #pragma unroll
        for (int r = 0; r < 4; ++r) {
            float v1 = INFINITY, v2 = INFINITY; int i1 = NCODE, i2 = NCODE;
            #pragma unroll
            for (int fj = 0; fj < 4; ++fj) {
                int nl = wcol + fj * 16 + lx;
                float s = ensh[nl] - 2.0f * acc[fi][fj][r];
                int code = n0 + nl;
                if (s < v1) { v2 = v1; i2 = i1; v1 = s; i1 = code; }
                else if (s < v2) { v2 = s; i2 = code; }
            }
            #pragma unroll
            for (int d = 1; d < 16; d <<= 1) {
                float ov1 = __shfl_xor(v1, d), ov2 = __shfl_xor(v2, d);
                int oi1 = __shfl_xor(i1, d), oi2 = __shfl_xor(i2, d);
                if (ov1 < v1) {
                    if (v1 < ov2) { v2 = v1; i2 = i1; } else { v2 = ov2; i2 = oi2; }
                    v1 = ov1; i1 = oi1;
                } else if (ov1 < v2) { v2 = ov1; i2 = oi1; }
            }
            if (lx == 0) {
                int row = wrow + fi * 16 + cg * 4 + r;
                bb[row * 2 + (wave >> 1)] = make_float4(v1, __int_as_float(i1),
                                                        v2, __int_as_float(i2));
            }
        }
    }
    __syncthreads();
    if (tid < 128) {
        float4 A4 = bb[tid * 2], C4 = bb[tid * 2 + 1];
        float v1, v2; int i1, i2;
        if (A4.x <= C4.x) {
            v1 = A4.x; i1 = __float_as_int(A4.y);
            if (A4.z <= C4.x) { v2 = A4.z; i2 = __float_as_int(A4.w); }
            else { v2 = C4.x; i2 = __float_as_int(C4.y); }
        } else {
            v1 = C4.x; i1 = __float_as_int(C4.y);
            if (C4.z <= A4.x) { v2 = C4.z; i2 = __float_as_int(C4.w); }
            else { v2 = A4.x; i2 = __float_as_int(A4.y); }
        }
        partial[(size_t)(m0 + tid) * 16 + bx] =
            make_float4(v1, __int_as_float(i1), v2, __int_as_float(i2));
    }
}

// ---------------- rescue: exact fp32 rescore of near-min candidates ----------------
__global__ __launch_bounds__(256) void k_rescue(
        const float4* __restrict__ partial, const float* __restrict__ qf,
        const float* __restrict__ E, const float* __restrict__ enorm,
        int* __restrict__ idxb) {
    int wid = (blockIdx.x * 256 + threadIdx.x) >> 6;   // one wave per query
    int lane = threadIdx.x & 63;
    float4 p;
    if (lane < 16) p = partial[(size_t)wid * 16 + lane];
    else p = make_float4(INFINITY, __int_as_float(NCODE), INFINITY, __int_as_float(NCODE));
    float bv = p.x;
    #pragma unroll
    for (int d = 1; d < 64; d <<= 1) bv = fminf(bv, __shfl_xor(bv, d));
    float thresh = bv + DELTA;
    unsigned long long m1 = __ballot(lane < 16 && p.x <= thresh);
    unsigned long long m2 = __ballot(lane < 16 && p.z <= thresh);
    const float* q = qf + (size_t)wid * 512 + lane * 8;
    float4 q0 = *(const float4*)q;
    float4 q1 = *(const float4*)(q + 4);
    float w = wseg(lane * 8);                 // segment bounds are multiples of 8
    float qw0 = q0.x * w, qw1 = q0.y * w, qw2 = q0.z * w, qw3 = q0.w * w;
    float qw4 = q1.x * w, qw5 = q1.y * w, qw6 = q1.z * w, qw7 = q1.w * w;
    float bs = INFINITY; int bi = NCODE;
    while (m1 | m2) {
        int ci;
        if (m1) {
            int src = __ffsll((long long)m1) - 1; m1 &= m1 - 1;
            ci = __shfl(__float_as_int(p.y), src);
        } else {
            int src = __ffsll((long long)m2) - 1; m2 &= m2 - 1;
            ci = __shfl(__float_as_int(p.w), src);
        }
        const float* e = E + (size_t)ci * 512 + lane * 8;
        float4 e0 = *(const float4*)e;
        float4 e1 = *(const float4*)(e + 4);
        float a = 0.f;
        a = fmaf(qw0, e0.x, a); a = fmaf(qw1, e0.y, a);
        a = fmaf(qw2, e0.z, a); a = fmaf(qw3, e0.w, a);
        a = fmaf(qw4, e1.x, a); a = fmaf(qw5, e1.y, a);
        a = fmaf(qw6, e1.z, a); a = fmaf(qw7, e1.w, a);
        #pragma unroll
        for (int d = 1; d < 64; d <<= 1) a += __shfl_xor(a, d);
        float s = enorm[ci] - 2.0f * a;
        if (s < bs || (s == bs && ci < bi)) { bs = s; bi = ci; }
    }
    if (lane == 0) idxb[wid] = bi;
}

// ---------------- fused update: rest-=upsample(E[idx]); dacc; emit next-scale q ----------------
// mode: 1=first (read f, dacc=), 2=last (write out=f-v, no q emit), 4=also emit qf32
__global__ __launch_bounds__(256) void k_update(
        const float* __restrict__ E, const int* __restrict__ idx,
        const float* __restrict__ f, float* __restrict__ rest,
        float* __restrict__ dacc, _Float16* __restrict__ q16n,
        float* __restrict__ qf32n, int pn, int sn, int mode) {
    int t = threadIdx.x;
    int pn_next = 1 << sn;
    int r = 64 >> sn;
    int b = blockIdx.x >> sn;
    int chunk = blockIdx.x & (pn_next - 1);
    float w0 = wseg(t), w1 = wseg(t + 256);
    float macc0 = 0.f, macc1 = 0.f;
    float pscale = (float)pn * (1.0f / 64.0f);
    __shared__ float redw[4];
    for (int ri = 0; ri < r; ++ri) {
        int n = chunk * r + ri;
        int row = (b << 6) + n;
        float srcp = fminf(fmaxf((n + 0.5f) * pscale - 0.5f, 0.0f), (float)(pn - 1));
        int i0 = (int)floorf(srcp);
        int i1 = min(i0 + 1, pn - 1);
        float wl = srcp - (float)i0;
        int cc0 = idx[b * pn + i0];
        int cc1 = idx[b * pn + i1];
        const float* e0 = E + (size_t)cc0 * 512;
        const float* e1 = E + (size_t)cc1 * 512;
        const float* rs = (mode & 1) ? f + (size_t)row * 512 : rest + (size_t)row * 512;
        float s = 0.f;
        {
            float h = (1.0f - wl) * e0[t] + wl * e1[t];
            float v = rs[t] - h;
            rest[(size_t)row * 512 + t] = (mode & 2) ? (f[(size_t)row * 512 + t] - v) : v;
            s = fmaf(w0 * v, v, s);
            macc0 += v;
        }
        {
            int c = t + 256;
            float h = (1.0f - wl) * e0[c] + wl * e1[c];
            float v = rs[c] - h;
            rest[(size_t)row * 512 + c] = (mode & 2) ? (f[(size_t)row * 512 + c] - v) : v;
            s = fmaf(w1 * v, v, s);
            macc1 += v;
        }
        #pragma unroll
        for (int d = 1; d < 64; d <<= 1) s += __shfl_xor(s, d);
        if ((t & 63) == 0) redw[t >> 6] = s;
        __syncthreads();
        if (t == 0) {
            float tot = redw[0] + redw[1] + redw[2] + redw[3];
            dacc[row] = (mode & 1) ? tot : dacc[row] + tot;
        }
        __syncthreads();
    }
    if (!(mode & 2)) {
        float inv = 1.0f / (float)r;
        size_t qrow = ((size_t)b << sn) + chunk;
        float m0v = macc0 * inv, m1v = macc1 * inv;
        q16n[qrow * 512 + t] = (_Float16)m0v;
        q16n[qrow * 512 + t + 256] = (_Float16)m1v;
        if (mode & 4) {
            qf32n[qrow * 512 + t] = m0v;
            qf32n[qrow * 512 + t + 256] = m1v;
        }
    }
}

// ---------------- finalize losses ----------------
__global__ void k_out12(const float* __restrict__ dacc, float* __restrict__ out) {
    int i = blockIdx.x * 256 + threadIdx.x; // 65536
    float d = dacc[i];
    out[i] = d * (0.25f / 7.0f);
    out[BN_ + i] = d * (1.0f / 7.0f);
}

extern "C" void kernel_launch(void* const* d_in, const int* in_sizes, int n_in,
                              void* d_out, int out_size, void* d_ws, size_t ws_size,
                              hipStream_t stream) {
    const float* f    = (const float*)d_in[0];
    const float* base = (const float*)d_in[1];
    const float* W    = (const float*)d_in[2];
    float* out = (float*)d_out;
    float* rest = out;                        // d_out doubles as f_rest

    char* ws = (char*)d_ws;
    float*     E      = (float*)ws;     ws += (size_t)NCODE * 512 * 4;    // 4 MB
    _Float16*  wek16  = (_Float16*)ws;  ws += (size_t)NCODE * 512 * 2;    // 2 MB
    _Float16*  q16a   = (_Float16*)ws;  ws += (size_t)32768 * 512 * 2;    // 32 MB (pn<=32 queries, f16)
    char*      big64  = ws;             ws += (size_t)65536 * 512 * 2;    // 64 MB (qf32 pn<=32 | q16 pn=64)
    float4*    partial= (float4*)ws;    ws += (size_t)65536 * 16 * 16;    // 16 MB
    float*     dacc   = (float*)ws;     ws += (size_t)BN_ * 4;
    int*       idxb   = (int*)ws;       ws += (size_t)BN_ * 4;
    float*     enorm  = (float*)ws;     ws += (size_t)NCODE * 4;

    k_gemm_e<<<dim3(NCODE / 64, 512 / 64), 256, 0, stream>>>(base, W, E);
    k_wek16<<<(NCODE * 512) / 256, 256, 0, stream>>>(E, wek16);
    k_enorm<<<NCODE / 256, 256, 0, stream>>>(E, enorm);
    k_down0<<<B_, 256, 0, stream>>>(f, q16a, (float*)big64);

    const int scales[7] = {1, 2, 4, 8, 16, 32, 64};
    for (int si = 0; si < 7; ++si) {
        int pn = scales[si];
        int M = 1024 * pn;
        const _Float16* q16s = (pn == 64) ? (const _Float16*)big64 : q16a;
        const float*    qfs  = (pn == 64) ? rest : (const float*)big64;

        k_score_f16<<<dim3(16, M / 128), 256, 0, stream>>>(q16s, wek16, enorm, partial);
        k_rescue<<<M / 4, 256, 0, stream>>>(partial, qfs, E, enorm, idxb);

        int pn_next = (si == 6) ? 64 : pn * 2;
        int sn = 0; while ((1 << sn) != pn_next) ++sn;
        int mode = (si == 0 ? 1 : 0) | (si == 6 ? 2 : 0) | ((si <= 4) ? 4 : 0);
        _Float16* q16n = (pn_next == 64) ? (_Float16*)big64 : q16a;
        k_update<<<1024 * pn_next, 256, 0, stream>>>(E, idxb, f, rest, dacc,
                                                     q16n, (float*)big64, pn, sn, mode);
    }

    k_out12<<<BN_ / 256, 256, 0, stream>>>(dacc, out + NTOT);
}